// Round 7
// baseline (542.478 us; speedup 1.0000x reference)
//
#include <hip/hip_runtime.h>

// z_i = mu[a_i] + tril(cov[a_i]) @ eps_i   (B=4194304, A=64, D=8)
//
// R4 post-mortem: 89us @ 2.4TB/s, VALUBusy 7.5%, bank-conflict 5.8M cyc.
// Latency-bound (BW low + VALU low + occupancy OK). HBM floor ~35us,
// LDS floor ~19us -> target ~55-65us via per-thread ILP:
//  - 4 rows/thread per iteration: 1x int4 annot + 8x float4 eps issued
//    upfront (9 independent VMEM ops in flight), then 4 independent
//    gather+FMA chains, then 8x 16B nontemporal stores (out never re-read).
//  - LDS tables unchanged: stride 65/9 scalar b32 gather (odd stride spreads
//    random annotators ~uniformly; b128 gather would re-concentrate into
//    16B bank windows and conflict worse).
// R5 fix: __builtin_nontemporal_store needs a clang ext_vector pointer,
// not HIP_vector_type float4* -> use f32x4 typedef for the stores.

#define THREADS 256
#define A_CNT 64
#define L_STRIDE 65   // 64 floats used + 1 pad (odd -> bank = (a + k) % 32)
#define MU_STRIDE 9

typedef float f32x4 __attribute__((ext_vector_type(4)));

__global__ __launch_bounds__(THREADS, 4) void latent_rsample_v2(
    const int* __restrict__ annot,
    const float* __restrict__ eps,
    const float* __restrict__ mu,
    const float* __restrict__ cov,
    float* __restrict__ out,
    int B)
{
    __shared__ float L_lds[A_CNT * L_STRIDE];
    __shared__ float mu_lds[A_CNT * MU_STRIDE];

    for (int e = threadIdx.x; e < A_CNT * 64; e += THREADS) {
        int a  = e >> 6;
        int rc = e & 63;
        L_lds[a * L_STRIDE + rc] = cov[e];
    }
    for (int e = threadIdx.x; e < A_CNT * 8; e += THREADS) {
        int a = e >> 3;
        int r = e & 7;
        mu_lds[a * MU_STRIDE + r] = mu[e];
    }
    __syncthreads();

    const int tid      = blockIdx.x * THREADS + threadIdx.x;
    const int nthreads = gridDim.x * THREADS;
    const int nbatch   = B >> 2;              // 4-row batches (B is 2^22)

    for (int b = tid; b < nbatch; b += nthreads) {
        const int base = b << 2;              // first row of this batch

        // Issue ALL independent loads upfront: 1x16B annot + 8x16B eps.
        const int4 a4 = *reinterpret_cast<const int4*>(annot + base);
        const float4* ep = reinterpret_cast<const float4*>(eps + (size_t)base * 8);
        float4 e[8];
        #pragma unroll
        for (int q = 0; q < 8; ++q) e[q] = ep[q];

        const int a_arr[4] = {a4.x, a4.y, a4.z, a4.w};
        f32x4* op = reinterpret_cast<f32x4*>(out + (size_t)base * 8);

        #pragma unroll
        for (int r4 = 0; r4 < 4; ++r4) {      // 4 independent rows
            const int a = a_arr[r4];
            const float* __restrict__ Lr = &L_lds[a * L_STRIDE];
            const float* __restrict__ mr = &mu_lds[a * MU_STRIDE];

            const float4 e0 = e[2 * r4];
            const float4 e1 = e[2 * r4 + 1];
            const float ef[8] = {e0.x, e0.y, e0.z, e0.w, e1.x, e1.y, e1.z, e1.w};

            float z[8];
            #pragma unroll
            for (int r = 0; r < 8; ++r) {
                float acc = mr[r];
                #pragma unroll
                for (int c = 0; c <= r; ++c)  // tril
                    acc += Lr[r * 8 + c] * ef[c];
                z[r] = acc;
            }

            // Output is write-once, never re-read: bypass cache pollution.
            f32x4 z0 = {z[0], z[1], z[2], z[3]};
            f32x4 z1 = {z[4], z[5], z[6], z[7]};
            __builtin_nontemporal_store(z0, op + 2 * r4);
            __builtin_nontemporal_store(z1, op + 2 * r4 + 1);
        }
    }

    // Generic tail (B % 4 != 0) — empty for B = 2^22.
    for (int i = (B & ~3) + tid; i < B; i += nthreads) {
        const int a = annot[i];
        const float* __restrict__ Lr = &L_lds[a * L_STRIDE];
        const float* __restrict__ mr = &mu_lds[a * MU_STRIDE];
        const float4* ep = reinterpret_cast<const float4*>(eps + (size_t)i * 8);
        const float4 e0 = ep[0];
        const float4 e1 = ep[1];
        const float ef[8] = {e0.x, e0.y, e0.z, e0.w, e1.x, e1.y, e1.z, e1.w};
        float z[8];
        #pragma unroll
        for (int r = 0; r < 8; ++r) {
            float acc = mr[r];
            #pragma unroll
            for (int c = 0; c <= r; ++c) acc += Lr[r * 8 + c] * ef[c];
            z[r] = acc;
        }
        float4* op = reinterpret_cast<float4*>(out + (size_t)i * 8);
        op[0] = make_float4(z[0], z[1], z[2], z[3]);
        op[1] = make_float4(z[4], z[5], z[6], z[7]);
    }
}

extern "C" void kernel_launch(void* const* d_in, const int* in_sizes, int n_in,
                              void* d_out, int out_size, void* d_ws, size_t ws_size,
                              hipStream_t stream) {
    const int*   annot = (const int*)  d_in[0];   // [B] int32
    const float* eps   = (const float*)d_in[1];   // [B, 8] f32
    const float* mu    = (const float*)d_in[2];   // [64, 8] f32
    const float* cov   = (const float*)d_in[3];   // [64, 8, 8] f32
    float* out = (float*)d_out;                   // [B, 8] f32

    const int B = in_sizes[0];                    // 4194304
    const int blocks = 2048;                      // 2 grid-stride iterations of 4-row batches

    latent_rsample_v2<<<blocks, THREADS, 0, stream>>>(annot, eps, mu, cov, out, B);
}

// Round 8
// 265.213 us; speedup vs baseline: 2.0454x; 2.0454x over previous
//
#include <hip/hip_runtime.h>

// z_i = mu[a_i] + tril(cov[a_i]) @ eps_i   (B=4194304, A=64, D=8)
//
// R4 (1 row/thread, coalesced): 89us, 2.4TB/s, WRITE 137MB, VALUBusy 7.5%.
// R7/v2 (4 consecutive rows/thread + nt stores): 387us, WRITE 277MB (2x!),
//   VALUBusy 1.9% -> batching consecutive rows gave every load/store a 128B
//   per-lane stride (1 lane per 64B line) and nt blocked L2 write merging.
// v3: ILP *without* breaking coalescing — unroll x4 across GRID-STRIDE
//   iterations (rows i, i+S, i+2S, i+3S). Within each instruction adjacent
//   lanes touch adjacent rows (R4's pattern), but 12 independent VMEM loads
//   issue upfront and 4 independent gather/FMA chains overlap. Plain stores.
//
// LDS tables unchanged: stride 65/9 scalar b32 gather; odd stride spreads the
// random annotator gather across banks (~2-4 lanes/bank).

#define THREADS 256
#define A_CNT 64
#define L_STRIDE 65   // 64 floats used + 1 pad (odd -> bank = (a + k) % 32)
#define MU_STRIDE 9

__global__ __launch_bounds__(THREADS) void latent_rsample_v3(
    const int* __restrict__ annot,
    const float* __restrict__ eps,
    const float* __restrict__ mu,
    const float* __restrict__ cov,
    float* __restrict__ out,
    int B)
{
    __shared__ float L_lds[A_CNT * L_STRIDE];
    __shared__ float mu_lds[A_CNT * MU_STRIDE];

    for (int e = threadIdx.x; e < A_CNT * 64; e += THREADS) {
        int a  = e >> 6;
        int rc = e & 63;
        L_lds[a * L_STRIDE + rc] = cov[e];
    }
    for (int e = threadIdx.x; e < A_CNT * 8; e += THREADS) {
        int a = e >> 3;
        int r = e & 7;
        mu_lds[a * MU_STRIDE + r] = mu[e];
    }
    __syncthreads();

    const int tid = blockIdx.x * THREADS + threadIdx.x;
    const int S   = gridDim.x * THREADS;          // 524288; B/S = 8 exactly

    int i0 = tid;
    // Unrolled-by-4 grid-stride: 4 rows far apart -> each row's access keeps
    // the lane-consecutive (coalesced) pattern; loads are independent -> ILP.
    for (; i0 + 3 * (long)S < B; i0 += 4 * S) {
        const int row[4] = {i0, i0 + S, i0 + 2 * S, i0 + 3 * S};

        // Issue all 12 independent loads upfront (4x annot, 8x float4 eps).
        int    a[4];
        float4 e0[4], e1[4];
        #pragma unroll
        for (int k = 0; k < 4; ++k) {
            a[k] = annot[row[k]];
            const float4* ep =
                reinterpret_cast<const float4*>(eps + (size_t)row[k] * 8);
            e0[k] = ep[0];
            e1[k] = ep[1];
        }

        #pragma unroll
        for (int k = 0; k < 4; ++k) {             // 4 independent chains
            const float* __restrict__ Lr = &L_lds[a[k] * L_STRIDE];
            const float* __restrict__ mr = &mu_lds[a[k] * MU_STRIDE];
            const float ef[8] = {e0[k].x, e0[k].y, e0[k].z, e0[k].w,
                                 e1[k].x, e1[k].y, e1[k].z, e1[k].w};

            float z[8];
            #pragma unroll
            for (int r = 0; r < 8; ++r) {
                float acc = mr[r];
                #pragma unroll
                for (int c = 0; c <= r; ++c)      // tril
                    acc += Lr[r * 8 + c] * ef[c];
                z[r] = acc;
            }

            float4* op = reinterpret_cast<float4*>(out + (size_t)row[k] * 8);
            op[0] = make_float4(z[0], z[1], z[2], z[3]);
            op[1] = make_float4(z[4], z[5], z[6], z[7]);
        }
    }

    // Generic tail (empty for B = 2^22 with 2048x256 grid).
    for (; i0 < B; i0 += S) {
        const int a = annot[i0];
        const float* __restrict__ Lr = &L_lds[a * L_STRIDE];
        const float* __restrict__ mr = &mu_lds[a * MU_STRIDE];
        const float4* ep = reinterpret_cast<const float4*>(eps + (size_t)i0 * 8);
        const float4 ea = ep[0];
        const float4 eb = ep[1];
        const float ef[8] = {ea.x, ea.y, ea.z, ea.w, eb.x, eb.y, eb.z, eb.w};
        float z[8];
        #pragma unroll
        for (int r = 0; r < 8; ++r) {
            float acc = mr[r];
            #pragma unroll
            for (int c = 0; c <= r; ++c) acc += Lr[r * 8 + c] * ef[c];
            z[r] = acc;
        }
        float4* op = reinterpret_cast<float4*>(out + (size_t)i0 * 8);
        op[0] = make_float4(z[0], z[1], z[2], z[3]);
        op[1] = make_float4(z[4], z[5], z[6], z[7]);
    }
}

extern "C" void kernel_launch(void* const* d_in, const int* in_sizes, int n_in,
                              void* d_out, int out_size, void* d_ws, size_t ws_size,
                              hipStream_t stream) {
    const int*   annot = (const int*)  d_in[0];   // [B] int32
    const float* eps   = (const float*)d_in[1];   // [B, 8] f32
    const float* mu    = (const float*)d_in[2];   // [64, 8] f32
    const float* cov   = (const float*)d_in[3];   // [64, 8, 8] f32
    float* out = (float*)d_out;                   // [B, 8] f32

    const int B = in_sizes[0];                    // 4194304
    const int blocks = 2048;                      // S=524288, 2 unrolled iters

    latent_rsample_v3<<<blocks, THREADS, 0, stream>>>(annot, eps, mu, cov, out, B);
}

// Round 9
// 252.275 us; speedup vs baseline: 2.1503x; 1.0513x over previous
//
#include <hip/hip_runtime.h>

// z_i = mu[a_i] + tril(cov[a_i]) @ eps_i   (B=4194304, A=64, D=8)
//
// History:
//  R4 (scalar b32 LDS gather, 1 row/thread): 89us, 2.4TB/s, VALUBusy 7.5%,
//     bank-conflict 5.8M cyc.
//  R7 (4 consecutive rows/thread + nt): 387us — broke coalescing (WRITE 2x).
//  R8 (grid-stride ILP x4, coalesced): 97us — ILP is NOT the limiter.
// Theory v4: co-bottleneck is the per-CU LDS pipe: 44 b32 gathers/row
//  (~345 cyc/row of LDS occupancy, ~37us/CU) serializing with the ~35us HBM
//  floor. Fix: pack tril(L) as 12 float4 groups + mu as 2 -> 14 ds_read_b128
//  per row (~168 cyc/row, ~18us). Layout strides 13 / 3 groups (odd ->
//  bank-group (13a+g)%8 spreads uniformly; 5 and 3 coprime to 8).
//  Everything else identical to R4 (1 row/thread, 2048x256 grid, float4 I/O).

#define THREADS 256
#define A_CNT 64
#define LP_STRIDE 13   // float4 groups per annotator: 12 used + 1 pad (odd)
#define MP_STRIDE 3    // float4 groups per annotator: 2 used + 1 pad (odd)

__global__ __launch_bounds__(THREADS) void latent_rsample_v4(
    const int* __restrict__ annot,
    const float* __restrict__ eps,
    const float* __restrict__ mu,
    const float* __restrict__ cov,
    float* __restrict__ out,
    int B)
{
    __shared__ float4 L_pack[A_CNT * LP_STRIDE];    // 13.0 KB
    __shared__ float4 mu_pack[A_CNT * MP_STRIDE];   //  3.0 KB

    const float4* cov4 = reinterpret_cast<const float4*>(cov); // 16 groups/annot
    const float4* mu4  = reinterpret_cast<const float4*>(mu);  //  2 groups/annot

    // Pack: group g of annotator a.
    //   g in [0,4):  row g,        cols 0-3   (rows 0-3 need 1 group)
    //   g in [4,12): row 4+(g-4)/2, cols ((g-4)&1)*4  (rows 4-7 need 2 groups)
    for (int e = threadIdx.x; e < A_CNT * 12; e += THREADS) {
        int a = e / 12;
        int g = e - a * 12;
        int row = (g < 4) ? g : 4 + ((g - 4) >> 1);
        int cg  = (g < 4) ? 0 : ((g - 4) & 1);
        L_pack[a * LP_STRIDE + g] = cov4[a * 16 + row * 2 + cg];
    }
    for (int e = threadIdx.x; e < A_CNT * 2; e += THREADS) {
        int a = e >> 1;
        int g = e & 1;
        mu_pack[a * MP_STRIDE + g] = mu4[a * 2 + g];
    }
    __syncthreads();

    const int stride = gridDim.x * THREADS;
    for (int i = blockIdx.x * THREADS + threadIdx.x; i < B; i += stride) {
        const int a = annot[i];

        const float4* ep = reinterpret_cast<const float4*>(eps + (size_t)i * 8);
        const float4 E0 = ep[0];
        const float4 E1 = ep[1];

        const float4* __restrict__ Lp = &L_pack[a * LP_STRIDE];
        const float4 m0 = mu_pack[a * MP_STRIDE];
        const float4 m1 = mu_pack[a * MP_STRIDE + 1];

        const float4 L0  = Lp[0],  L1  = Lp[1], L2  = Lp[2],  L3  = Lp[3];
        const float4 L4a = Lp[4],  L4b = Lp[5];
        const float4 L5a = Lp[6],  L5b = Lp[7];
        const float4 L6a = Lp[8],  L6b = Lp[9];
        const float4 L7a = Lp[10], L7b = Lp[11];

        const float z0 = m0.x + L0.x*E0.x;
        const float z1 = m0.y + L1.x*E0.x + L1.y*E0.y;
        const float z2 = m0.z + L2.x*E0.x + L2.y*E0.y + L2.z*E0.z;
        const float z3 = m0.w + L3.x*E0.x + L3.y*E0.y + L3.z*E0.z + L3.w*E0.w;
        const float z4 = m1.x + L4a.x*E0.x + L4a.y*E0.y + L4a.z*E0.z + L4a.w*E0.w
                              + L4b.x*E1.x;
        const float z5 = m1.y + L5a.x*E0.x + L5a.y*E0.y + L5a.z*E0.z + L5a.w*E0.w
                              + L5b.x*E1.x + L5b.y*E1.y;
        const float z6 = m1.z + L6a.x*E0.x + L6a.y*E0.y + L6a.z*E0.z + L6a.w*E0.w
                              + L6b.x*E1.x + L6b.y*E1.y + L6b.z*E1.z;
        const float z7 = m1.w + L7a.x*E0.x + L7a.y*E0.y + L7a.z*E0.z + L7a.w*E0.w
                              + L7b.x*E1.x + L7b.y*E1.y + L7b.z*E1.z + L7b.w*E1.w;

        float4* op = reinterpret_cast<float4*>(out + (size_t)i * 8);
        op[0] = make_float4(z0, z1, z2, z3);
        op[1] = make_float4(z4, z5, z6, z7);
    }
}

extern "C" void kernel_launch(void* const* d_in, const int* in_sizes, int n_in,
                              void* d_out, int out_size, void* d_ws, size_t ws_size,
                              hipStream_t stream) {
    const int*   annot = (const int*)  d_in[0];   // [B] int32
    const float* eps   = (const float*)d_in[1];   // [B, 8] f32
    const float* mu    = (const float*)d_in[2];   // [64, 8] f32
    const float* cov   = (const float*)d_in[3];   // [64, 8, 8] f32
    float* out = (float*)d_out;                   // [B, 8] f32

    const int B = in_sizes[0];                    // 4194304
    const int blocks = 2048;                      // 8 grid-stride rows/thread

    latent_rsample_v4<<<blocks, THREADS, 0, stream>>>(annot, eps, mu, cov, out, B);
}